// Round 2
// baseline (341.884 us; speedup 1.0000x reference)
//
#include <hip/hip_runtime.h>

constexpr int WPB = 4;   // waves (=tokens) per block

// One wave per token. Element e (0..2047) decomposes phase-1 as e = 32*t + j
// (t = lane, j = reg 0..31): FHT bits 0..4 in-register. LDS transpose, then
// phase-2 lane u=2*j0+b holds e = 1024*b + 32*r + j0 (r = reg): FHT bits 5..9
// in-register, bit 10 via shfl_xor(1) (quad_perm DPP, cheap).
__global__ __launch_bounds__(256, 4) void e8rht_kernel(
    const int* __restrict__ input_ids,
    const int* __restrict__ Qidxs,        // int16 widened to int32 by harness
    const int* __restrict__ Qidxs2,
    const float* __restrict__ codebook,   // fp16 upcast to f32: row = 8 floats
    const float* __restrict__ codebook2,
    const float* __restrict__ SV,         // fp16 upcast to f32
    const float* __restrict__ Wscale,
    const float* __restrict__ inv_resid,
    float* __restrict__ out)              // fp16 output delivered as f32
{
    __shared__ __align__(16) float lds[WPB * 2048];
    const int wave = threadIdx.x >> 6;
    const int lane = threadIdx.x & 63;
    const int tok  = blockIdx.x * WPB + wave;

    const float ws  = Wscale[0];
    const float ws2 = ws * inv_resid[0];
    const int tid = input_ids[tok];

    const int4 q1 = *(const int4*)(Qidxs  + tid * 256 + lane * 4);
    const int4 q2 = *(const int4*)(Qidxs2 + tid * 256 + lane * 4);

    float v[32];
    {
        const int i1[4] = { q1.x & 0xFFFF, q1.y & 0xFFFF, q1.z & 0xFFFF, q1.w & 0xFFFF };
        const int i2[4] = { q2.x & 0xFFFF, q2.y & 0xFFFF, q2.z & 0xFFFF, q2.w & 0xFFFF };
        #pragma unroll
        for (int c = 0; c < 4; ++c) {
            const float4* r1 = (const float4*)(codebook  + (size_t)i1[c] * 8);
            const float4* r2 = (const float4*)(codebook2 + (size_t)i2[c] * 8);
            const float4 a0 = r1[0], a1 = r1[1];
            const float4 b0 = r2[0], b1 = r2[1];
            v[8*c + 0] = a0.x * ws + b0.x * ws2;
            v[8*c + 1] = a0.y * ws + b0.y * ws2;
            v[8*c + 2] = a0.z * ws + b0.z * ws2;
            v[8*c + 3] = a0.w * ws + b0.w * ws2;
            v[8*c + 4] = a1.x * ws + b1.x * ws2;
            v[8*c + 5] = a1.y * ws + b1.y * ws2;
            v[8*c + 6] = a1.z * ws + b1.z * ws2;
            v[8*c + 7] = a1.w * ws + b1.w * ws2;
        }
    }

    // FHT bits 0..4 (within-thread)
    #pragma unroll
    for (int h = 1; h < 32; h <<= 1) {
        #pragma unroll
        for (int r = 0; r < 32; ++r) {
            if ((r & h) == 0) {
                float a = v[r], b = v[r + h];
                v[r] = a + b;
                v[r + h] = a - b;
            }
        }
    }

    // Transposed LDS write: element (row j, col t) at row j, swizzled col.
    // col' = ((t>>2) ^ (j&15))*4 + (t&3)  -> 2 lanes/bank (free on gfx950).
    float* L = lds + wave * 2048;
    {
        const int t4 = lane >> 2, tl = lane & 3;
        #pragma unroll
        for (int j = 0; j < 32; ++j) {
            const int col = (((t4 ^ (j & 15)) << 2) | tl);
            L[(j << 6) + col] = v[j];
        }
    }
    __syncthreads();

    // Phase 2: lane u = 2*j0 + b reads row j0, cols t = 32b..32b+31.
    const int j0 = lane >> 1;
    const int b  = lane & 1;
    float w[32];
    {
        const float4* Lr = (const float4*)(L + (j0 << 6));
        #pragma unroll
        for (int c = 0; c < 8; ++c) {
            const int ch = ((b << 3) + c) ^ (j0 & 15);  // stored chunk of t4 = 8b+c
            const float4 f = Lr[ch];
            w[4*c + 0] = f.x; w[4*c + 1] = f.y; w[4*c + 2] = f.z; w[4*c + 3] = f.w;
        }
    }

    // FHT bits 5..9 (within-thread, over r)
    #pragma unroll
    for (int h = 1; h < 32; h <<= 1) {
        #pragma unroll
        for (int r = 0; r < 32; ++r) {
            if ((r & h) == 0) {
                float a = w[r], bb = w[r + h];
                w[r] = a + bb;
                w[r + h] = a - bb;
            }
        }
    }

    // FHT bit 10: partner lane u^1 (quad_perm DPP)
    #pragma unroll
    for (int r = 0; r < 32; ++r) {
        const float o = __shfl_xor(w[r], 1, 64);
        w[r] = b ? (o - w[r]) : (w[r] + o);
    }

    // SV multiply + f32 store: e = 1024*b + 32*r + j0
    // Per r, the wave writes two contiguous 128 B segments — coalesced.
    const size_t obase = (size_t)tok * 2048;
    const int ebase = (b << 10) | j0;
    #pragma unroll
    for (int r = 0; r < 32; ++r) {
        const int e = ebase + (r << 5);
        out[obase + e] = w[r] * SV[e];
    }
}

extern "C" void kernel_launch(void* const* d_in, const int* in_sizes, int n_in,
                              void* d_out, int out_size, void* d_ws, size_t ws_size,
                              hipStream_t stream) {
    const int* input_ids   = (const int*)d_in[0];
    const int* Qidxs       = (const int*)d_in[1];
    const int* Qidxs2      = (const int*)d_in[2];
    const float* codebook  = (const float*)d_in[3];
    const float* codebook2 = (const float*)d_in[4];
    const float* SV        = (const float*)d_in[5];
    const float* wscale    = (const float*)d_in[6];
    const float* irs       = (const float*)d_in[7];
    float* out             = (float*)d_out;

    const int n_tok = in_sizes[0];          // 8*2048 = 16384
    const int grid  = n_tok / WPB;          // 4096 blocks of 256 threads
    e8rht_kernel<<<grid, 256, 0, stream>>>(input_ids, Qidxs, Qidxs2,
                                           codebook, codebook2, SV,
                                           wscale, irs, out);
}

// Round 3
// 319.542 us; speedup vs baseline: 1.0699x; 1.0699x over previous
//
#include <hip/hip_runtime.h>
#include <hip/hip_fp16.h>

constexpr int WPB = 4;   // waves (=tokens) per block

typedef int   v4i __attribute__((ext_vector_type(4)));
typedef unsigned int v4u __attribute__((ext_vector_type(4)));

// ---------- pre-pass: f32 codebooks -> fp16 (lossless, data was fp16) ------
__global__ __launch_bounds__(256) void cvt_kernel(
    const float* __restrict__ cb1, const float* __restrict__ cb2,
    unsigned int* __restrict__ o1, unsigned int* __restrict__ o2)
{
    const int r = blockIdx.x * 256 + threadIdx.x;        // 0..131071
    const float* src = (r < 65536) ? (cb1 + (size_t)r * 8)
                                   : (cb2 + (size_t)(r - 65536) * 8);
    unsigned int* dst = (r < 65536) ? (o1 + (size_t)r * 4)
                                    : (o2 + (size_t)(r - 65536) * 4);
    const float4 a = ((const float4*)src)[0];
    const float4 b = ((const float4*)src)[1];
    __half2 h0 = __floats2half2_rn(a.x, a.y);
    __half2 h1 = __floats2half2_rn(a.z, a.w);
    __half2 h2 = __floats2half2_rn(b.x, b.y);
    __half2 h3 = __floats2half2_rn(b.z, b.w);
    v4u o;
    o.x = *(unsigned int*)&h0; o.y = *(unsigned int*)&h1;
    o.z = *(unsigned int*)&h2; o.w = *(unsigned int*)&h3;
    *(v4u*)dst = o;
}

// ---------- main kernel (fp16 codebook gathers) ----------------------------
__global__ __launch_bounds__(256, 4) void e8rht_kernel_h(
    const int* __restrict__ input_ids,
    const int* __restrict__ Qidxs,
    const int* __restrict__ Qidxs2,
    const unsigned int* __restrict__ cb1h,   // fp16 pairs: row = 4 uints (16 B)
    const unsigned int* __restrict__ cb2h,
    const float* __restrict__ SV,
    const float* __restrict__ Wscale,
    const float* __restrict__ inv_resid,
    float* __restrict__ out)
{
    __shared__ __align__(16) float lds[WPB * 2048];
    const int wave = threadIdx.x >> 6;
    const int lane = threadIdx.x & 63;
    const int tok  = blockIdx.x * WPB + wave;

    const float ws  = Wscale[0];
    const float ws2 = ws * inv_resid[0];
    const int tid = input_ids[tok];

    // streaming reads: non-temporal (keep L2 for codebooks)
    const v4i q1 = __builtin_nontemporal_load((const v4i*)(Qidxs  + (size_t)tid * 256 + lane * 4));
    const v4i q2 = __builtin_nontemporal_load((const v4i*)(Qidxs2 + (size_t)tid * 256 + lane * 4));

    float v[32];
    {
        const int i1[4] = { q1.x & 0xFFFF, q1.y & 0xFFFF, q1.z & 0xFFFF, q1.w & 0xFFFF };
        const int i2[4] = { q2.x & 0xFFFF, q2.y & 0xFFFF, q2.z & 0xFFFF, q2.w & 0xFFFF };
        #pragma unroll
        for (int c = 0; c < 4; ++c) {
            const v4u a = *(const v4u*)(cb1h + (size_t)i1[c] * 4);   // 16 B
            const v4u b = *(const v4u*)(cb2h + (size_t)i2[c] * 4);
            const unsigned int au[4] = { a.x, a.y, a.z, a.w };
            const unsigned int bu[4] = { b.x, b.y, b.z, b.w };
            #pragma unroll
            for (int p = 0; p < 4; ++p) {
                const float2 fa = __half22float2(*(const __half2*)&au[p]);
                const float2 fb = __half22float2(*(const __half2*)&bu[p]);
                v[8*c + 2*p]     = fa.x * ws + fb.x * ws2;
                v[8*c + 2*p + 1] = fa.y * ws + fb.y * ws2;
            }
        }
    }

    // FHT bits 0..4 (within-thread)
    #pragma unroll
    for (int h = 1; h < 32; h <<= 1) {
        #pragma unroll
        for (int r = 0; r < 32; ++r) {
            if ((r & h) == 0) {
                float a = v[r], b = v[r + h];
                v[r] = a + b;
                v[r + h] = a - b;
            }
        }
    }

    // Transposed LDS write (wave-private region, wave-synchronous — no block
    // barrier needed). col' = ((t>>2) ^ (j&15))*4 + (t&3): 2 lanes/bank, free.
    float* L = lds + wave * 2048;
    {
        const int t4 = lane >> 2, tl = lane & 3;
        #pragma unroll
        for (int j = 0; j < 32; ++j) {
            const int col = (((t4 ^ (j & 15)) << 2) | tl);
            L[(j << 6) + col] = v[j];
        }
    }
    __builtin_amdgcn_wave_barrier();   // pin ordering; lgkmcnt inserted by compiler

    // Phase 2: lane u = 2*j0 + b reads row j0, cols t = 32b..32b+31.
    const int j0 = lane >> 1;
    const int b  = lane & 1;
    float w[32];
    {
        const float4* Lr = (const float4*)(L + (j0 << 6));
        #pragma unroll
        for (int c = 0; c < 8; ++c) {
            const int ch = ((b << 3) + c) ^ (j0 & 15);
            const float4 f = Lr[ch];
            w[4*c + 0] = f.x; w[4*c + 1] = f.y; w[4*c + 2] = f.z; w[4*c + 3] = f.w;
        }
    }

    // FHT bits 5..9 (within-thread)
    #pragma unroll
    for (int h = 1; h < 32; h <<= 1) {
        #pragma unroll
        for (int r = 0; r < 32; ++r) {
            if ((r & h) == 0) {
                float a = w[r], bb = w[r + h];
                w[r] = a + bb;
                w[r + h] = a - bb;
            }
        }
    }

    // FHT bit 10: partner lane u^1 (quad_perm DPP)
    #pragma unroll
    for (int r = 0; r < 32; ++r) {
        const float o = __shfl_xor(w[r], 1, 64);
        w[r] = b ? (o - w[r]) : (w[r] + o);
    }

    // SV multiply + non-temporal f32 store: e = 1024*b + 32*r + j0
    const size_t obase = (size_t)tok * 2048;
    const int ebase = (b << 10) | j0;
    #pragma unroll
    for (int r = 0; r < 32; ++r) {
        const int e = ebase + (r << 5);
        __builtin_nontemporal_store(w[r] * SV[e], &out[obase + e]);
    }
}

// ---------- fallback (round-2 kernel, f32 gathers) — used if ws too small --
__global__ __launch_bounds__(256, 4) void e8rht_kernel_f(
    const int* __restrict__ input_ids,
    const int* __restrict__ Qidxs,
    const int* __restrict__ Qidxs2,
    const float* __restrict__ codebook,
    const float* __restrict__ codebook2,
    const float* __restrict__ SV,
    const float* __restrict__ Wscale,
    const float* __restrict__ inv_resid,
    float* __restrict__ out)
{
    __shared__ __align__(16) float lds[WPB * 2048];
    const int wave = threadIdx.x >> 6;
    const int lane = threadIdx.x & 63;
    const int tok  = blockIdx.x * WPB + wave;

    const float ws  = Wscale[0];
    const float ws2 = ws * inv_resid[0];
    const int tid = input_ids[tok];

    const int4 q1 = *(const int4*)(Qidxs  + (size_t)tid * 256 + lane * 4);
    const int4 q2 = *(const int4*)(Qidxs2 + (size_t)tid * 256 + lane * 4);

    float v[32];
    {
        const int i1[4] = { q1.x & 0xFFFF, q1.y & 0xFFFF, q1.z & 0xFFFF, q1.w & 0xFFFF };
        const int i2[4] = { q2.x & 0xFFFF, q2.y & 0xFFFF, q2.z & 0xFFFF, q2.w & 0xFFFF };
        #pragma unroll
        for (int c = 0; c < 4; ++c) {
            const float4* r1 = (const float4*)(codebook  + (size_t)i1[c] * 8);
            const float4* r2 = (const float4*)(codebook2 + (size_t)i2[c] * 8);
            const float4 a0 = r1[0], a1 = r1[1];
            const float4 b0 = r2[0], b1 = r2[1];
            v[8*c+0]=a0.x*ws+b0.x*ws2; v[8*c+1]=a0.y*ws+b0.y*ws2;
            v[8*c+2]=a0.z*ws+b0.z*ws2; v[8*c+3]=a0.w*ws+b0.w*ws2;
            v[8*c+4]=a1.x*ws+b1.x*ws2; v[8*c+5]=a1.y*ws+b1.y*ws2;
            v[8*c+6]=a1.z*ws+b1.z*ws2; v[8*c+7]=a1.w*ws+b1.w*ws2;
        }
    }
    #pragma unroll
    for (int h = 1; h < 32; h <<= 1)
        #pragma unroll
        for (int r = 0; r < 32; ++r)
            if ((r & h) == 0) { float a=v[r],b=v[r+h]; v[r]=a+b; v[r+h]=a-b; }

    float* L = lds + wave * 2048;
    {
        const int t4 = lane >> 2, tl = lane & 3;
        #pragma unroll
        for (int j = 0; j < 32; ++j)
            L[(j << 6) + (((t4 ^ (j & 15)) << 2) | tl)] = v[j];
    }
    __syncthreads();
    const int j0 = lane >> 1;
    const int b  = lane & 1;
    float w[32];
    {
        const float4* Lr = (const float4*)(L + (j0 << 6));
        #pragma unroll
        for (int c = 0; c < 8; ++c) {
            const float4 f = Lr[((b << 3) + c) ^ (j0 & 15)];
            w[4*c+0]=f.x; w[4*c+1]=f.y; w[4*c+2]=f.z; w[4*c+3]=f.w;
        }
    }
    #pragma unroll
    for (int h = 1; h < 32; h <<= 1)
        #pragma unroll
        for (int r = 0; r < 32; ++r)
            if ((r & h) == 0) { float a=w[r],bb=w[r+h]; w[r]=a+bb; w[r+h]=a-bb; }
    #pragma unroll
    for (int r = 0; r < 32; ++r) {
        const float o = __shfl_xor(w[r], 1, 64);
        w[r] = b ? (o - w[r]) : (w[r] + o);
    }
    const size_t obase = (size_t)tok * 2048;
    const int ebase = (b << 10) | j0;
    #pragma unroll
    for (int r = 0; r < 32; ++r) {
        const int e = ebase + (r << 5);
        out[obase + e] = w[r] * SV[e];
    }
}

extern "C" void kernel_launch(void* const* d_in, const int* in_sizes, int n_in,
                              void* d_out, int out_size, void* d_ws, size_t ws_size,
                              hipStream_t stream) {
    const int* input_ids   = (const int*)d_in[0];
    const int* Qidxs       = (const int*)d_in[1];
    const int* Qidxs2      = (const int*)d_in[2];
    const float* codebook  = (const float*)d_in[3];
    const float* codebook2 = (const float*)d_in[4];
    const float* SV        = (const float*)d_in[5];
    const float* wscale    = (const float*)d_in[6];
    const float* irs       = (const float*)d_in[7];
    float* out             = (float*)d_out;

    const int n_tok = in_sizes[0];          // 16384
    const int grid  = n_tok / WPB;          // 4096 blocks

    const size_t cb_h_bytes = (size_t)65536 * 8 * 2;   // 1 MB per codebook
    if (ws_size >= 2 * cb_h_bytes) {
        unsigned int* cb1h = (unsigned int*)d_ws;
        unsigned int* cb2h = (unsigned int*)((char*)d_ws + cb_h_bytes);
        cvt_kernel<<<512, 256, 0, stream>>>(codebook, codebook2, cb1h, cb2h);
        e8rht_kernel_h<<<grid, 256, 0, stream>>>(input_ids, Qidxs, Qidxs2,
                                                 cb1h, cb2h, SV, wscale, irs, out);
    } else {
        e8rht_kernel_f<<<grid, 256, 0, stream>>>(input_ids, Qidxs, Qidxs2,
                                                 codebook, codebook2, SV,
                                                 wscale, irs, out);
    }
}